// Round 2
// baseline (14678.355 us; speedup 1.0000x reference)
//
#include <hip/hip_runtime.h>
#include <math.h>
#include <stdint.h>

#define BB   2048
#define TT   100
#define DD   128
#define HH   256
#define NEGF -1.0e9f

typedef __attribute__((ext_vector_type(8))) short short8_t;   // 8 bf16 = 4 VGPR
typedef __attribute__((ext_vector_type(4))) float f32x4;

#define MFMA16(a,b,c) __builtin_amdgcn_mfma_f32_16x16x32_bf16((a),(b),(c),0,0,0)

__device__ __forceinline__ float sigmoidf_(float x){ return 1.0f/(1.0f+expf(-x)); }

// fast tanh for scores only: HW exp + HW rcp. |rel err| ~1e-7.
__device__ __forceinline__ float tanh_fast(float x){
  x = fminf(15.f, fmaxf(-15.f, x));
  const float e = __expf(x + x);
  return (e - 1.f) * __builtin_amdgcn_rcpf(e + 1.f);
}

// 3-way bf16 split: x == h + m + l EXACTLY (24 mantissa bits covered).
// h = RNE(x); rem = x-h exact (<=15 bits); m = RNE(rem); rem2 = rem-m exact
// (<=8 significant bits -> fits bf16 exactly, truncation is lossless).
__device__ __forceinline__ void bf16_split3(float x, unsigned short &h,
                                            unsigned short &m, unsigned short &l){
  const unsigned u = __float_as_uint(x);
  const unsigned r = u + 0x7FFFu + ((u >> 16) & 1u);
  h = (unsigned short)(r >> 16);
  const float rem = x - __uint_as_float(r & 0xFFFF0000u);
  const unsigned u2 = __float_as_uint(rem);
  const unsigned r2 = u2 + 0x7FFFu + ((u2 >> 16) & 1u);
  m = (unsigned short)(r2 >> 16);
  const float rem2 = rem - __uint_as_float(r2 & 0xFFFF0000u);
  l = (unsigned short)(__float_as_uint(rem2) >> 16);
}

__global__ __launch_bounds__(256) void k_split3(const float* __restrict__ src,
    unsigned short* __restrict__ hi, unsigned short* __restrict__ mi,
    unsigned short* __restrict__ lo, int n){
  const int i = blockIdx.x*256 + threadIdx.x;
  if(i < n){ unsigned short h,m,l; bf16_split3(src[i], h, m, l);
             hi[i]=h; mi[i]=m; lo[i]=l; }
}

__global__ __launch_bounds__(256) void k_zero_i32(int* __restrict__ p, int n){
  int i = blockIdx.x*256 + threadIdx.x;
  if(i < n) p[i] = 0;
}

// 6-product bf16x6 accumulate, small terms first (mm,hl,lh ~2^-16; hm,mh ~2^-8; hh ~1)
#define MFMA_X6(aH,aM,aL,bH,bM,bL,acc)            \
  do{ acc = MFMA16(aM, bM, acc);                  \
      acc = MFMA16(aH, bL, acc);                  \
      acc = MFMA16(aL, bH, acc);                  \
      acc = MFMA16(aH, bM, acc);                  \
      acc = MFMA16(aM, bH, acc);                  \
      acc = MFMA16(aH, bH, acc); }while(0)

// Fused gates GEMM (bf16x6 MFMA) + LSTM cell.
// Block: 128 thr = 2 waves; tile 64 m-rows x 64 n-cols (16 j-cols x 4 gate strips,
// strip in FRAGMENT index: c = strip*16 + jj -> lane holds all 4 gates of col j).
// grid (16,32) = 512 blocks.  A (fp32) split3 during staging; W pre-split [n][k].
__global__ __launch_bounds__(128) void k_gates_cell(
    const float* __restrict__ Xp, int ldx,          // may be null (x==0)
    const float* __restrict__ Hp,                   // may be null (h==0)
    const unsigned short* __restrict__ WihH, const unsigned short* __restrict__ WihM,
    const unsigned short* __restrict__ WihL,
    const unsigned short* __restrict__ WhhH, const unsigned short* __restrict__ WhhM,
    const unsigned short* __restrict__ WhhL,
    const float* __restrict__ bih, const float* __restrict__ bhh,
    const float* __restrict__ Cp,                   // may be null (c==0)
    float* __restrict__ Hout, float* __restrict__ Cout,
    float* __restrict__ Hcopy, int hstride)         // optional extra h sink
{
  // pad rows to 40 ushorts (80 B): 16B-aligned b128 frags, 2-way banks only (free)
  __shared__ alignas(16) unsigned short AsH[64*40], AsM[64*40], AsL[64*40];
  __shared__ alignas(16) unsigned short WsH[64*40], WsM[64*40], WsL[64*40];
  const int tid  = threadIdx.x;
  const int lane = tid & 63;
  const int wv   = tid >> 6;
  const int l15  = lane & 15;
  const int l4   = lane >> 4;
  const int j0   = blockIdx.x * 16;
  const int m0   = blockIdx.y * 64;

  f32x4 acc[2][4];
  #pragma unroll
  for(int a=0;a<2;a++)
    #pragma unroll
    for(int s=0;s<4;s++)
      #pragma unroll
      for(int e=0;e<4;e++) acc[a][s][e] = 0.f;

  for(int phase=0; phase<2; phase++){
    const float* Am; int lda;
    const unsigned short *WH, *WM, *WL; int ldw, nt;
    if(phase==0){ if(!Xp) continue; Am=Xp; lda=ldx;
                  WH=WihH; WM=WihM; WL=WihL; ldw=DD; nt=4; }
    else        { if(!Hp) continue; Am=Hp; lda=HH;
                  WH=WhhH; WM=WhhM; WL=WhhL; ldw=HH; nt=8; }
    for(int kt=0; kt<nt; kt++){
      const int k0 = kt*32;
      __syncthreads();                              // protect LDS vs prev-iter reads
      // stage A: 64 rows x 32 k fp32 -> 3x bf16 (512 float4 / 128 thr)
      #pragma unroll
      for(int it=0; it<4; it++){
        const int q  = it*128 + tid;
        const int r  = q >> 3;
        const int kq = (q & 7) << 2;
        const float4 v = *(const float4*)(Am + (size_t)(m0+r)*lda + k0 + kq);
        unsigned short h0,m0_,l0,h1,m1_,l1,h2,m2_,l2,h3,m3_,l3;
        bf16_split3(v.x,h0,m0_,l0); bf16_split3(v.y,h1,m1_,l1);
        bf16_split3(v.z,h2,m2_,l2); bf16_split3(v.w,h3,m3_,l3);
        *(ushort4*)&AsH[r*40+kq] = make_ushort4(h0,h1,h2,h3);
        *(ushort4*)&AsM[r*40+kq] = make_ushort4(m0_,m1_,m2_,m3_);
        *(ushort4*)&AsL[r*40+kq] = make_ushort4(l0,l1,l2,l3);
      }
      // stage W: 64 c-rows x 32 k, c = strip*16+jj -> global row strip*HH+j0+jj
      #pragma unroll
      for(int half=0; half<3; half++){
        const unsigned short* __restrict__ Wg = (half==0)?WH:((half==1)?WM:WL);
        unsigned short* Ws = (half==0)?WsH:((half==1)?WsM:WsL);
        #pragma unroll
        for(int it=0; it<2; it++){
          const int q  = it*128 + tid;
          const int c  = q >> 2;
          const int kq = (q & 3) << 3;
          const int n  = ((c>>4)*HH) + j0 + (c & 15);
          *(uint4*)&Ws[c*40+kq] = *(const uint4*)(Wg + (size_t)n*ldw + k0 + kq);
        }
      }
      __syncthreads();
      short8_t aH[2], aM[2], aL[2];
      #pragma unroll
      for(int fm=0; fm<2; fm++){
        const int r = wv*32 + fm*16 + l15;
        aH[fm] = *(const short8_t*)&AsH[r*40 + l4*8];
        aM[fm] = *(const short8_t*)&AsM[r*40 + l4*8];
        aL[fm] = *(const short8_t*)&AsL[r*40 + l4*8];
      }
      #pragma unroll
      for(int s=0; s<4; s++){
        const int c = s*16 + l15;
        const short8_t bH = *(const short8_t*)&WsH[c*40 + l4*8];
        const short8_t bM = *(const short8_t*)&WsM[c*40 + l4*8];
        const short8_t bL = *(const short8_t*)&WsL[c*40 + l4*8];
        #pragma unroll
        for(int fm=0; fm<2; fm++){
          MFMA_X6(aH[fm],aM[fm],aL[fm], bH,bM,bL, acc[fm][s]);
        }
      }
    }
  }

  // cell epilogue, lane-local: lane owns col j = j0+l15, gate = frag idx s.
  // D layout (m89-verified): col = lane&15, row = (lane>>4)*4 + reg.
  const int j = j0 + l15;
  const float bi0 = bih[       j] + bhh[       j];
  const float bf0 = bih[  HH + j] + bhh[  HH + j];
  const float bg0 = bih[2*HH + j] + bhh[2*HH + j];
  const float bo0 = bih[3*HH + j] + bhh[3*HH + j];
  #pragma unroll
  for(int fm=0; fm<2; fm++){
    #pragma unroll
    for(int r=0; r<4; r++){
      const int m = m0 + wv*32 + fm*16 + l4*4 + r;
      const size_t idx = (size_t)m*HH + j;
      const float iv = acc[fm][0][r] + bi0;
      const float fv = acc[fm][1][r] + bf0;
      const float gv = acc[fm][2][r] + bg0;
      const float ov = acc[fm][3][r] + bo0;
      const float cp = Cp ? Cp[idx] : 0.f;
      const float cn = sigmoidf_(fv)*cp + sigmoidf_(iv)*tanhf(gv);
      const float hn = sigmoidf_(ov)*tanhf(cn);
      Cout[idx] = cn;
      Hout[idx] = hn;
      if(Hcopy) Hcopy[(size_t)m*hstride + j] = hn;
    }
  }
}

// blend2 = h @ W2^T  (2048x256, K=256), bf16x6 MFMA.
// Block: 128 thr, tile 32m x 64n; grid (4,64) = 256 blocks.
__global__ __launch_bounds__(128) void k_blend2(
    const float* __restrict__ Hin,
    const unsigned short* __restrict__ W2H, const unsigned short* __restrict__ W2M,
    const unsigned short* __restrict__ W2L,
    float* __restrict__ out)
{
  __shared__ alignas(16) unsigned short AsH[32*40], AsM[32*40], AsL[32*40];
  __shared__ alignas(16) unsigned short WsH[64*40], WsM[64*40], WsL[64*40];
  const int tid  = threadIdx.x;
  const int lane = tid & 63;
  const int wv   = tid >> 6;
  const int l15  = lane & 15;
  const int l4   = lane >> 4;
  const int n0   = blockIdx.x * 64;
  const int m0   = blockIdx.y * 32;

  f32x4 acc[4];
  #pragma unroll
  for(int s=0;s<4;s++)
    #pragma unroll
    for(int e=0;e<4;e++) acc[s][e] = 0.f;

  for(int kt=0; kt<8; kt++){
    const int k0 = kt*32;
    __syncthreads();
    #pragma unroll
    for(int it=0; it<2; it++){
      const int q  = it*128 + tid;                  // 0..255
      const int r  = q >> 3;
      const int kq = (q & 7) << 2;
      const float4 v = *(const float4*)(Hin + (size_t)(m0+r)*HH + k0 + kq);
      unsigned short h0,m0_,l0,h1,m1_,l1,h2,m2_,l2,h3,m3_,l3;
      bf16_split3(v.x,h0,m0_,l0); bf16_split3(v.y,h1,m1_,l1);
      bf16_split3(v.z,h2,m2_,l2); bf16_split3(v.w,h3,m3_,l3);
      *(ushort4*)&AsH[r*40+kq] = make_ushort4(h0,h1,h2,h3);
      *(ushort4*)&AsM[r*40+kq] = make_ushort4(m0_,m1_,m2_,m3_);
      *(ushort4*)&AsL[r*40+kq] = make_ushort4(l0,l1,l2,l3);
    }
    #pragma unroll
    for(int half=0; half<3; half++){
      const unsigned short* __restrict__ Wg = (half==0)?W2H:((half==1)?W2M:W2L);
      unsigned short* Ws = (half==0)?WsH:((half==1)?WsM:WsL);
      #pragma unroll
      for(int it=0; it<2; it++){
        const int q  = it*128 + tid;
        const int c  = q >> 2;
        const int kq = (q & 3) << 3;
        const int n  = n0 + c;
        *(uint4*)&Ws[c*40+kq] = *(const uint4*)(Wg + (size_t)n*HH + k0 + kq);
      }
    }
    __syncthreads();
    const int r = wv*16 + l15;
    const short8_t aH = *(const short8_t*)&AsH[r*40 + l4*8];
    const short8_t aM = *(const short8_t*)&AsM[r*40 + l4*8];
    const short8_t aL = *(const short8_t*)&AsL[r*40 + l4*8];
    #pragma unroll
    for(int s=0; s<4; s++){
      const int c = s*16 + l15;
      const short8_t bH = *(const short8_t*)&WsH[c*40 + l4*8];
      const short8_t bM = *(const short8_t*)&WsM[c*40 + l4*8];
      const short8_t bL = *(const short8_t*)&WsL[c*40 + l4*8];
      MFMA_X6(aH,aM,aL, bH,bM,bL, acc[s]);
    }
  }
  #pragma unroll
  for(int s=0; s<4; s++)
    #pragma unroll
    for(int r=0; r<4; r++)
      out[(size_t)(m0 + wv*16 + l4*4 + r)*HH + n0 + s*16 + l15] = acc[s][r];
}

// In-place row transform: blend1_rows <- blend1_rows @ W1^T, bf16x6 MFMA.
// Block: 128 thr (2 waves), owns 32 full rows (all 256 out-cols -> in-place safe).
__global__ __launch_bounds__(128) void k_blend1(
    float* __restrict__ blend1,
    const unsigned short* __restrict__ W1H, const unsigned short* __restrict__ W1M,
    const unsigned short* __restrict__ W1L)
{
  __shared__ alignas(16) unsigned short AsH[32*264], AsM[32*264], AsL[32*264];
  const int tid  = threadIdx.x;
  const int lane = tid & 63;
  const int wv   = tid >> 6;
  const int l15  = lane & 15;
  const int l4   = lane >> 4;
  const size_t r0 = (size_t)blockIdx.x * 32;

  #pragma unroll
  for(int it=0; it<16; it++){
    const int q  = it*128 + tid;                    // 0..2047
    const int r  = q >> 6;
    const int kq = (q & 63) << 2;
    const float4 v = *(const float4*)(blend1 + (r0+r)*256 + kq);
    unsigned short h0,m0_,l0,h1,m1_,l1,h2,m2_,l2,h3,m3_,l3;
    bf16_split3(v.x,h0,m0_,l0); bf16_split3(v.y,h1,m1_,l1);
    bf16_split3(v.z,h2,m2_,l2); bf16_split3(v.w,h3,m3_,l3);
    *(ushort4*)&AsH[r*264+kq] = make_ushort4(h0,h1,h2,h3);
    *(ushort4*)&AsM[r*264+kq] = make_ushort4(m0_,m1_,m2_,m3_);
    *(ushort4*)&AsL[r*264+kq] = make_ushort4(l0,l1,l2,l3);
  }
  __syncthreads();

  f32x4 acc[16];
  #pragma unroll
  for(int s=0;s<16;s++)
    #pragma unroll
    for(int e=0;e<4;e++) acc[s][e] = 0.f;

  const int rb = wv*16;                             // wave's row base
  for(int kt=0; kt<8; kt++){
    const int k0 = kt*32;
    const short8_t aH = *(const short8_t*)&AsH[(rb+l15)*264 + k0 + l4*8];
    const short8_t aM = *(const short8_t*)&AsM[(rb+l15)*264 + k0 + l4*8];
    const short8_t aL = *(const short8_t*)&AsL[(rb+l15)*264 + k0 + l4*8];
    #pragma unroll
    for(int fn=0; fn<16; fn++){
      const int n = fn*16 + l15;
      const short8_t bH = *(const short8_t*)(W1H + (size_t)n*256 + k0 + l4*8);
      const short8_t bM = *(const short8_t*)(W1M + (size_t)n*256 + k0 + l4*8);
      const short8_t bL = *(const short8_t*)(W1L + (size_t)n*256 + k0 + l4*8);
      MFMA_X6(aH,aM,aL, bH,bM,bL, acc[fn]);
    }
  }
  #pragma unroll
  for(int fn=0; fn<16; fn++)
    #pragma unroll
    for(int r=0; r<4; r++)
      blend1[(r0 + rb + l4*4 + r)*256 + fn*16 + l15] = acc[fn][r];
}

// Pointer scores + argmax + softmax + gather.  One block per batch row. (unchanged)
__global__ __launch_bounds__(256) void k_scores(
    const float* __restrict__ blend1,   // [B,T,256]
    const float* __restrict__ blend2,   // [B,256]
    const float* __restrict__ vt,       // [256]
    const float* __restrict__ targets,  // [B,T,128]
    int*  __restrict__ selected,        // [B,T]
    float* __restrict__ dec_in,         // [B,128]
    float* __restrict__ out,            // [B,T,T]
    int s)
{
  __shared__ float vt_s[256], b2_s[256], sc[128];
  __shared__ float M_s, S_s;
  __shared__ int sel_s;
  const int b = blockIdx.x;
  const int tid = threadIdx.x;
  const int lane = tid & 63;
  const int wave = tid >> 6;

  vt_s[tid] = vt[tid];
  b2_s[tid] = blend2[(size_t)b*256 + tid];
  __syncthreads();

  const float4 bb = *(const float4*)&b2_s[lane*4];
  const float4 vv = *(const float4*)&vt_s[lane*4];

  for(int it=0; it<25; it++){
    const int t = wave + it*4;
    const float4 x = *(const float4*)(blend1 + ((size_t)b*TT + t)*256 + lane*4);
    float p;
    p = tanh_fast(x.x + bb.x) * vv.x;
    p = fmaf(tanh_fast(x.y + bb.y), vv.y, p);
    p = fmaf(tanh_fast(x.z + bb.z), vv.z, p);
    p = fmaf(tanh_fast(x.w + bb.w), vv.w, p);
    #pragma unroll
    for(int off=32; off>=1; off>>=1) p += __shfl_xor(p, off, 64);
    if(lane == 0) sc[t] = p;
  }
  __syncthreads();

  if(wave == 0){
    float m1 = selected[(size_t)b*TT + lane] ? NEGF : sc[lane];
    sc[lane] = m1;
    float bestv = m1; int besti = lane;
    float m2 = 0.f;
    const int t2 = lane + 64;
    if(t2 < TT){
      m2 = selected[(size_t)b*TT + t2] ? NEGF : sc[t2];
      sc[t2] = m2;
      if(m2 > bestv){ bestv = m2; besti = t2; }
    }
    #pragma unroll
    for(int off=32; off>=1; off>>=1){
      const float ov = __shfl_xor(bestv, off, 64);
      const int   oi = __shfl_xor(besti, off, 64);
      if(ov > bestv || (ov == bestv && oi < besti)){ bestv = ov; besti = oi; }
    }
    float e = __expf(m1 - bestv);
    if(t2 < TT) e += __expf(m2 - bestv);
    #pragma unroll
    for(int off=32; off>=1; off>>=1) e += __shfl_xor(e, off, 64);
    if(lane == 0){
      M_s = bestv; S_s = e; sel_s = besti;
      selected[(size_t)b*TT + besti] = 1;
    }
  }
  __syncthreads();

  const int sel = sel_s;
  if(tid < TT){
    float p = __expf(sc[tid] - M_s) / S_s;
    out[(size_t)b*TT*TT + (size_t)s*TT + tid] = fmaxf(p, 1e-9f);
  }
  if(tid < DD){
    dec_in[(size_t)b*DD + tid] = targets[((size_t)b*TT + sel)*DD + tid];
  }
}

extern "C" void kernel_launch(void* const* d_in, const int* in_sizes, int n_in,
                              void* d_out, int out_size, void* d_ws, size_t ws_size,
                              hipStream_t stream)
{
  (void)in_sizes; (void)n_in; (void)out_size; (void)ws_size;
  const float* targets  = (const float*)d_in[0];
  const float* h0       = (const float*)d_in[1];
  const float* c0       = (const float*)d_in[2];
  const float* enc_w_ih = (const float*)d_in[3];
  const float* enc_w_hh = (const float*)d_in[4];
  const float* enc_b_ih = (const float*)d_in[5];
  const float* enc_b_hh = (const float*)d_in[6];
  const float* dec_w_ih = (const float*)d_in[7];
  const float* dec_w_hh = (const float*)d_in[8];
  const float* dec_b_ih = (const float*)d_in[9];
  const float* dec_b_hh = (const float*)d_in[10];
  const float* W1       = (const float*)d_in[11];
  const float* W2       = (const float*)d_in[12];
  const float* vt       = (const float*)d_in[13];
  float* out = (float*)d_out;

  // workspace carve-up (~228 MB)
  float* ws      = (float*)d_ws;
  float* blend1  = ws;                               // B*T*256
  float* hA      = blend1 + (size_t)BB*TT*256;       // B*256 each
  float* hB      = hA + (size_t)BB*HH;
  float* cA      = hB + (size_t)BB*HH;
  float* cB      = cA + (size_t)BB*HH;
  float* blend2  = cB + (size_t)BB*HH;               // B*256
  float* dec_in  = blend2 + (size_t)BB*HH;           // B*128
  int*   selected= (int*)(dec_in + (size_t)BB*DD);   // B*T ints

  // bf16 3-way weight arena (~5.5 MB), 64B-aligned
  char* pc = (char*)(selected + (size_t)BB*TT);
  pc = (char*)(((uintptr_t)pc + 63) & ~(uintptr_t)63);
  unsigned short* q = (unsigned short*)pc;
  unsigned short* ewihH = q; q += (size_t)1024*128;
  unsigned short* ewihM = q; q += (size_t)1024*128;
  unsigned short* ewihL = q; q += (size_t)1024*128;
  unsigned short* ewhhH = q; q += (size_t)1024*256;
  unsigned short* ewhhM = q; q += (size_t)1024*256;
  unsigned short* ewhhL = q; q += (size_t)1024*256;
  unsigned short* dwihH = q; q += (size_t)1024*128;
  unsigned short* dwihM = q; q += (size_t)1024*128;
  unsigned short* dwihL = q; q += (size_t)1024*128;
  unsigned short* dwhhH = q; q += (size_t)1024*256;
  unsigned short* dwhhM = q; q += (size_t)1024*256;
  unsigned short* dwhhL = q; q += (size_t)1024*256;
  unsigned short* w1H   = q; q += (size_t)256*256;
  unsigned short* w1M   = q; q += (size_t)256*256;
  unsigned short* w1L   = q; q += (size_t)256*256;
  unsigned short* w2H   = q; q += (size_t)256*256;
  unsigned short* w2M   = q; q += (size_t)256*256;
  unsigned short* w2L   = q; q += (size_t)256*256;

  k_split3<<<(1024*128+255)/256, 256, 0, stream>>>(enc_w_ih, ewihH, ewihM, ewihL, 1024*128);
  k_split3<<<(1024*256+255)/256, 256, 0, stream>>>(enc_w_hh, ewhhH, ewhhM, ewhhL, 1024*256);
  k_split3<<<(1024*128+255)/256, 256, 0, stream>>>(dec_w_ih, dwihH, dwihM, dwihL, 1024*128);
  k_split3<<<(1024*256+255)/256, 256, 0, stream>>>(dec_w_hh, dwhhH, dwhhM, dwhhL, 1024*256);
  k_split3<<<(256*256+255)/256,  256, 0, stream>>>(W1, w1H, w1M, w1L, 256*256);
  k_split3<<<(256*256+255)/256,  256, 0, stream>>>(W2, w2H, w2M, w2L, 256*256);

  k_zero_i32<<<(BB*TT + 255)/256, 256, 0, stream>>>(selected, BB*TT);

  // ---- encoder: h written both to h-buffer and into blend1 slot (pre-W1) ----
  for(int t=0; t<TT; t++){
    const float* Hp = (t==0) ? nullptr : ((t&1) ? hA : hB);
    const float* Cp = (t==0) ? nullptr : ((t&1) ? cA : cB);
    float* Ho = (t&1) ? hB : hA;
    float* Co = (t&1) ? cB : cA;
    k_gates_cell<<<dim3(16,32), 128, 0, stream>>>(
        targets + (size_t)t*DD, TT*DD,
        Hp, ewihH, ewihM, ewihL, ewhhH, ewhhM, ewhhL, enc_b_ih, enc_b_hh, Cp,
        Ho, Co, blend1 + (size_t)t*256, TT*256);
  }

  // ---- blend1 = enc_states @ W1^T, in place ----
  k_blend1<<<BB*TT/32, 128, 0, stream>>>(blend1, w1H, w1M, w1L);

  // ---- decoder ----
  for(int s=0; s<TT; s++){
    const float* Hp = (s==0) ? h0 : ((s&1) ? hA : hB);
    const float* Cp = (s==0) ? c0 : ((s&1) ? cA : cB);
    float* Ho = (s&1) ? hB : hA;
    float* Co = (s&1) ? cB : cA;
    const float* Xp = (s==0) ? nullptr : dec_in;   // first input is zeros
    k_gates_cell<<<dim3(16,32), 128, 0, stream>>>(
        Xp, DD, Hp, dwihH, dwihM, dwihL, dwhhH, dwhhM, dwhhL, dec_b_ih, dec_b_hh, Cp,
        Ho, Co, nullptr, 0);
    k_blend2<<<dim3(4,64), 128, 0, stream>>>(Ho, w2H, w2M, w2L, blend2);
    k_scores<<<BB, 256, 0, stream>>>(blend1, blend2, vt, targets, selected,
                                     dec_in, out, s);
  }
}